// Round 2
// baseline (310.324 us; speedup 1.0000x reference)
//
#include <hip/hip_runtime.h>

// Problem constants
#define B_  8
#define C_  64
#define O_  64
#define H_  80
#define W_  800
#define NCHT   13           // prep kernel: ceil(800/64) 64-px transpose tiles
#define NCHM   25           // main kernel: 800/32 exact 32-px chunks
#define XT_BYTES 65536000u  // 8*80*800*64*2

#define ROWS_ 10            // staged halo rows: h0-3 .. h0+6 (4 output rows)
#define ROWB_ 5120          // 40 px * 128 B per staged row (cols w0-3..w0+36)
#define LDSX_BYTES (ROWS_ * ROWB_ + 1024)   // 52224 B -> 3 blocks/CU @ 512 thr

typedef short bf16x8 __attribute__((ext_vector_type(8)));
typedef float f32x4  __attribute__((ext_vector_type(4)));

__device__ __forceinline__ unsigned short f2bf(float f) {
    unsigned int u = __float_as_uint(f);
    unsigned int r = u + 0x7FFFu + ((u >> 16) & 1u);   // RNE
    return (unsigned short)(r >> 16);
}

__device__ __forceinline__ void gld_lds16(const void* g, void* l) {
    __builtin_amdgcn_global_load_lds(
        (const __attribute__((address_space(1))) unsigned int*)g,
        (__attribute__((address_space(3))) unsigned int*)l, 16, 0, 0);
}

// ---------------------------------------------------------------------------
// Kernel 1 (merged): x (B,C,H,W) fp32 -> xT bf16 pixel-major with SWIZZLED
// channel groups (group g of pixel w at position (g+w)&7), PLUS weight
// pre-swizzle in tail blocks (blockIdx.y >= H_). Phase-2 uses px=lane so the
// LDS column read is 2-way-aliased only (free) instead of 4-way.
// ---------------------------------------------------------------------------
__global__ void k_prep(const float* __restrict__ x, const float* __restrict__ wt,
                       unsigned short* __restrict__ xT, unsigned short* __restrict__ wf) {
    __shared__ float tile[64][68];
    const int tid = threadIdx.x;

    if (blockIdx.y >= H_) {
        // ---- weight fragment path: 208 blocks cover 36864 elements ----
        const int idx = ((int)(blockIdx.y - H_) * B_ + (int)blockIdx.z) * NCHT + (int)blockIdx.x;
        const int t = idx * 256 + tid;
        if (t < 36864) {
            const int j    = t & 7;
            const int lane = (t >> 3) & 63;
            const int mt   = (t >> 9) & 3;
            const int ks   = t >> 11;                   // 0..17
            const int tap  = ks >> 1, hf = ks & 1;
            const int o = mt * 16 + (lane & 15);
            const int c = hf * 32 + (lane >> 4) * 8 + j;
            wf[t] = f2bf(wt[(tap * 64 + o) * 64 + c]);
        }
        return;
    }

    const int chunk = blockIdx.x, h = blockIdx.y, b = blockIdx.z;
    const int w0 = chunk * 64;

    // phase 1: stage 64ch x 64px fp32 tile (coalesced float4 per channel)
    const int wf4 = tid & 15;
    const int c0  = tid >> 4;
    const int w   = w0 + wf4 * 4;       // W%4==0: float4 all-valid or all-invalid
#pragma unroll
    for (int it = 0; it < 4; ++it) {
        const int c = it * 16 + c0;
        f32x4 v = {0.f, 0.f, 0.f, 0.f};
        if (w < W_) v = *(const f32x4*)(x + (((b * C_ + c) * H_ + h) * W_) + w);
        *(f32x4*)&tile[c][wf4 * 4] = v;
    }
    __syncthreads();

    // phase 2: lane owns pixel px=lane; wave wv owns ch-groups 2wv, 2wv+1.
    // bank = (8i + px) & 31 over px=0..63 -> 2-way alias only (free).
    const int wv = tid >> 6, px = tid & 63;
    const int wabs = w0 + px;
    if (wabs < W_) {
        unsigned int u[8];
#pragma unroll
        for (int i = 0; i < 8; ++i) {
            const int c = wv * 16 + 2 * i;
            u[i] = (unsigned int)f2bf(tile[c][px])
                 | ((unsigned int)f2bf(tile[c + 1][px]) << 16);
        }
        unsigned int* base = (unsigned int*)xT + ((size_t)((b * H_ + h) * W_) + wabs) * 32;
        const int g0 = (2 * wv + wabs) & 7;
        const int g1 = (2 * wv + 1 + wabs) & 7;
        *(uint4*)(base + g0 * 4) = make_uint4(u[0], u[1], u[2], u[3]);
        *(uint4*)(base + g1 * 4) = make_uint4(u[4], u[5], u[6], u[7]);
    }
}

// ---------------------------------------------------------------------------
// Kernel 2: gather-GEMM, 4-output-row blocks (h-quads), 32-px chunks.
// Block = 512 thr = 8 waves over (4 h rows) x (2 o-halves).
// Stage rows h0-3..h0+6 (10 slots, 51.2 KB) via global_load_lds; row-halo
// staging amplification is 2.5x (was 4x with h-pairs). 52224 B LDS ->
// 3 blocks/CU = 24 waves/CU (was 12). Per-wave inner loop identical to the
// h-pair version: acc[2][2], B dist-1 LDS prefetch, A dist-2 global prefetch.
// ---------------------------------------------------------------------------
__global__ void __launch_bounds__(512, 6)
k_main(const unsigned short* __restrict__ xT,
       const unsigned short* __restrict__ wfrag,
       const float* __restrict__ dh, const float* __restrict__ dw,
       const float* __restrict__ bias, float* __restrict__ out) {
    __shared__ char lx[LDSX_BYTES];
    const int tid  = threadIdx.x;
    const int wave = tid >> 6, lane = tid & 63;

    const unsigned int flat = blockIdx.x;           // 0..3999
    const int b = flat & 7;                         // XCD swizzle: batch per XCD
    const unsigned int l = flat >> 3;               // 0..499
    const int chunk = l % NCHM;
    const int hq    = l / NCHM;                     // 0..19
    const int h0 = hq * 4;
    const int w0 = chunk * 32;
    const int h   = h0 + (wave & 3);
    const int mtb = (wave >> 2) * 2;                // o-half: mt in {mtb, mtb+1}
    const int l15 = lane & 15, kq = lane >> 4;

    // ---- Stage halo: slot = wave, plus slots 8,9 by waves 0,1 ----
    {
        const int col0  = (w0 - 3) < 0 ? 0 : (w0 - 3);
        const int shift = (col0 - (w0 - 3)) * 128;  // 0 or 384 (chunk 0)
#pragma unroll
        for (int k = 0; k < 2; ++k) {
            const int slot = wave + k * 8;
            if (slot < ROWS_) {
                int ar = h0 - 3 + slot;
                ar = ar < 0 ? 0 : (ar > H_ - 1 ? H_ - 1 : ar);
                const char* src = (const char*)xT
                    + ((size_t)(b * H_ + ar) * W_ + col0) * 128;
                char* dst = lx + slot * ROWB_ + shift;
#pragma unroll
                for (int i = 0; i < 5; ++i)
                    gld_lds16(src + i * 1024 + lane * 16, dst + i * 1024);
            }
        }
    }

    // ---- Per-pixel gather addresses (LDS byte offsets) ----
    // 25*32 == 800 exactly: pw < W_ always, no clamps needed.
    unsigned int rowb[2][3], colb[2][3];
#pragma unroll
    for (int nt = 0; nt < 2; ++nt) {
        const int pw  = w0 + nt * 16 + l15;
        const int dhi = (int)dh[b * W_ + pw];
        const int dwi = (int)dw[b * W_ + pw];
        int rD = h - dhi;   if (rD < 0) rD = -rD;
        const int rU = (h + dhi < H_) ? (h + dhi) : h;
        int cL = pw - dwi;  if (cL < 0) cL = -cL;
        const int cR = (pw + dwi < W_) ? (pw + dwi) : (2 * W_ - 1 - pw - dwi);
        rowb[nt][0] = (unsigned int)(rD - h0 + 3) * ROWB_;
        rowb[nt][1] = (unsigned int)(h  - h0 + 3) * ROWB_;
        rowb[nt][2] = (unsigned int)(rU - h0 + 3) * ROWB_;
        const int cs[3] = {cL, pw, cR};
#pragma unroll
        for (int j = 0; j < 3; ++j)
            colb[nt][j] = (unsigned int)(cs[j] - (w0 - 3)) * 128u
                        + (unsigned int)(((cs[j] + kq) & 7) * 16);
    }

    const char* wfb = (const char*)wfrag;
    const unsigned int aoff = (unsigned int)lane * 16u;

    // acc init = bias
    f32x4 acc[2][2];
#pragma unroll
    for (int mtl = 0; mtl < 2; ++mtl) {
        const f32x4 bv = *(const f32x4*)(bias + (mtb + mtl) * 16 + kq * 4);
#pragma unroll
        for (int nt = 0; nt < 2; ++nt)
#pragma unroll
            for (int r = 0; r < 4; ++r) acc[mtl][nt][r] = bv[r];
    }

    __syncthreads();   // staging complete (compiler drains vmcnt here)

    // ---- K loop: 18 steps; B dist-1 (LDS), A dist-2 (global) prefetch ----
    bf16x8 bcur[2], bnxt[2], a0[2], a1[2], a2[2];
#pragma unroll
    for (int nt = 0; nt < 2; ++nt)
        bcur[nt] = *(const bf16x8*)(lx + rowb[nt][0] + colb[nt][0]);
#pragma unroll
    for (int mtl = 0; mtl < 2; ++mtl) {
        a0[mtl] = *(const bf16x8*)(wfb + (unsigned int)((0 * 4 + mtb + mtl) * 1024) + aoff);
        a1[mtl] = *(const bf16x8*)(wfb + (unsigned int)((1 * 4 + mtb + mtl) * 1024) + aoff);
    }

#pragma unroll
    for (int s = 0; s < 18; ++s) {
        if (s < 17) {
            const int sn = s + 1;
            const int tap = sn >> 1, hf = sn & 1;
            const int i = tap / 3, j = tap % 3;
#pragma unroll
            for (int nt = 0; nt < 2; ++nt) {
                unsigned int a = rowb[nt][i] + colb[nt][j];
                if (hf) a ^= 64u;                  // ch-group +4 under swizzle
                bnxt[nt] = *(const bf16x8*)(lx + a);
            }
        }
        if (s < 16) {
#pragma unroll
            for (int mtl = 0; mtl < 2; ++mtl)
                a2[mtl] = *(const bf16x8*)(wfb
                            + (unsigned int)(((s + 2) * 4 + mtb + mtl) * 1024) + aoff);
        }
#pragma unroll
        for (int mtl = 0; mtl < 2; ++mtl)
#pragma unroll
            for (int nt = 0; nt < 2; ++nt)
                acc[mtl][nt] = __builtin_amdgcn_mfma_f32_16x16x32_bf16(
                    a0[mtl], bcur[nt], acc[mtl][nt], 0, 0, 0);
#pragma unroll
        for (int nt = 0; nt < 2; ++nt) bcur[nt] = bnxt[nt];
#pragma unroll
        for (int mtl = 0; mtl < 2; ++mtl) { a0[mtl] = a1[mtl]; a1[mtl] = a2[mtl]; }
    }

    // ---- Epilogue: out[b][o][h][w] (w always < W_: exact chunking) ----
#pragma unroll
    for (int mtl = 0; mtl < 2; ++mtl) {
#pragma unroll
        for (int nt = 0; nt < 2; ++nt) {
            const int w = w0 + nt * 16 + l15;
            const unsigned int ob =
                ((unsigned int)(b * O_ + (mtb + mtl) * 16 + kq * 4) * (unsigned int)H_
                 + (unsigned int)h) * (unsigned int)W_ + (unsigned int)w;
#pragma unroll
            for (int r = 0; r < 4; ++r)
                out[ob + (unsigned int)r * 64000u] = acc[mtl][nt][r];
        }
    }
}

extern "C" void kernel_launch(void* const* d_in, const int* in_sizes, int n_in,
                              void* d_out, int out_size, void* d_ws, size_t ws_size,
                              hipStream_t stream) {
    const float* x      = (const float*)d_in[0];   // (8,64,80,800)
    const float* dh     = (const float*)d_in[1];   // (8,1,800)
    const float* dw     = (const float*)d_in[2];   // (8,1,800)
    const float* weight = (const float*)d_in[3];   // (9,64,64)
    const float* bias   = (const float*)d_in[4];   // (64,)
    float* out = (float*)d_out;

    unsigned short* xT    = (unsigned short*)d_ws;
    unsigned short* wfrag = (unsigned short*)((char*)d_ws + XT_BYTES);

    k_prep<<<dim3(NCHT, H_ + 2, B_), 256, 0, stream>>>(x, weight, xT, wfrag);
    k_main<<<dim3(NCHM * (H_ / 4) * B_), 512, 0, stream>>>(xT, wfrag, dh, dw, bias, out);
}

// Round 3
// 307.797 us; speedup vs baseline: 1.0082x; 1.0082x over previous
//
#include <hip/hip_runtime.h>

// Problem constants
#define B_  8
#define C_  64
#define O_  64
#define H_  80
#define W_  800
#define NCHM   25          // main kernel: 800/32 exact 32-px chunks

#define ROWS_  10          // staged halo rows: h0-3 .. h0+6 (4 output rows)
#define ROWPX_ 40          // staged cols w0-3 .. w0+36
#define ROWB_  (ROWPX_ * 128)          // 5120 B per staged row
#define LDSX_BYTES (ROWS_ * ROWB_)     // 51200 B (no pad: stage is per-slot exact)

typedef short bf16x8 __attribute__((ext_vector_type(8)));
typedef float f32x4  __attribute__((ext_vector_type(4)));

__device__ __forceinline__ unsigned short f2bf(float f) {
    unsigned int u = __float_as_uint(f);
    unsigned int r = u + 0x7FFFu + ((u >> 16) & 1u);   // RNE
    return (unsigned short)(r >> 16);
}

// ---------------------------------------------------------------------------
// Kernel 1: pre-swizzle weight (9,O,C) fp32 into exact A-fragment order, bf16.
// Tiny (144 blocks); the only prep pass left.
// ---------------------------------------------------------------------------
__global__ void k_wfrag(const float* __restrict__ wt, unsigned short* __restrict__ wf) {
    const int t = blockIdx.x * 256 + threadIdx.x;   // < 36864
    const int j    = t & 7;
    const int lane = (t >> 3) & 63;
    const int mt   = (t >> 9) & 3;
    const int ks   = t >> 11;                       // 0..17
    const int tap  = ks >> 1, hf = ks & 1;
    const int o = mt * 16 + (lane & 15);
    const int c = hf * 32 + (lane >> 4) * 8 + j;
    wf[t] = f2bf(wt[(tap * 64 + o) * 64 + c]);
}

// ---------------------------------------------------------------------------
// Kernel 2: FUSED transpose + gather-GEMM. Single pass over x.
// Block = 512 thr = 8 waves over (4 h rows) x (2 o-halves); 32-px chunk.
//
// Stage phase (replaces the old k_transpose + xT round-trip): 80 tasks
// (row 0..9, ch-group g 0..7); wave w owns tasks 10w..10w+9; lanes 0..39 are
// pixel columns (colabs = w0-3+lane). Per task: 8 coalesced (160B/instr)
// stride-H*W f32 loads -> f2bf RNE pack -> one swizzled ds_write_b128 into
// the SAME pixel-major bf16 layout the verified gather expects:
//   lx[row*ROWB + (colabs-(w0-3))*128 + ((g+colabs)&7)*16]
// Row-halo x re-reads (2.5x) are L2-absorbed (10-row band = 2 MB < 4 MB/XCD).
//
// Gather/K-loop/epilogue identical to the verified two-pass version.
// ---------------------------------------------------------------------------
__global__ void __launch_bounds__(512, 4)
k_main(const float* __restrict__ x,
       const unsigned short* __restrict__ wfrag,
       const float* __restrict__ dh, const float* __restrict__ dw,
       const float* __restrict__ bias, float* __restrict__ out) {
    __shared__ char lx[LDSX_BYTES];
    const int tid  = threadIdx.x;
    const int wave = tid >> 6, lane = tid & 63;

    const unsigned int flat = blockIdx.x;           // 0..3999
    const int b = flat & 7;                         // XCD swizzle: batch per XCD
    const unsigned int l = flat >> 3;               // 0..499
    const int chunk = l % NCHM;
    const int hq    = l / NCHM;                     // 0..19
    const int h0 = hq * 4;
    const int w0 = chunk * 32;
    const int h   = h0 + (wave & 3);
    const int mtb = (wave >> 2) * 2;                // o-half: mt in {mtb, mtb+1}
    const int l15 = lane & 15, kq = lane >> 4;

    // ---- Fused stage: x fp32 -> lx bf16 (transpose + convert + swizzle) ----
    {
        const int colabs = w0 - 3 + lane;           // lane = px slot
        if (lane < ROWPX_ && colabs >= 0 && colabs < W_) {
#pragma unroll
            for (int t = 0; t < 10; ++t) {
                const int task = wave * 10 + t;     // 0..79
                const int row = task >> 3, g = task & 7;
                int ar = h0 - 3 + row;
                ar = ar < 0 ? 0 : (ar > H_ - 1 ? H_ - 1 : ar);
                const float* src = x + ((size_t)(b * C_ + g * 8) * H_ + ar) * W_ + colabs;
                float v[8];
#pragma unroll
                for (int c = 0; c < 8; ++c) v[c] = src[(size_t)c * (H_ * W_)];
                unsigned int u[4];
#pragma unroll
                for (int i = 0; i < 4; ++i)
                    u[i] = (unsigned int)f2bf(v[2 * i])
                         | ((unsigned int)f2bf(v[2 * i + 1]) << 16);
                char* dst = lx + (unsigned int)row * (unsigned int)ROWB_
                          + (unsigned int)lane * 128u
                          + (unsigned int)(((g + colabs) & 7) * 16);
                *(uint4*)dst = make_uint4(u[0], u[1], u[2], u[3]);
            }
        }
    }

    // ---- Per-pixel gather addresses (LDS byte offsets) ----
    // 25*32 == 800 exactly: pw < W_ always, no clamps needed.
    unsigned int rowb[2][3], colb[2][3];
#pragma unroll
    for (int nt = 0; nt < 2; ++nt) {
        const int pw  = w0 + nt * 16 + l15;
        const int dhi = (int)dh[b * W_ + pw];
        const int dwi = (int)dw[b * W_ + pw];
        int rD = h - dhi;   if (rD < 0) rD = -rD;
        const int rU = (h + dhi < H_) ? (h + dhi) : h;
        int cL = pw - dwi;  if (cL < 0) cL = -cL;
        const int cR = (pw + dwi < W_) ? (pw + dwi) : (2 * W_ - 1 - pw - dwi);
        rowb[nt][0] = (unsigned int)(rD - h0 + 3) * ROWB_;
        rowb[nt][1] = (unsigned int)(h  - h0 + 3) * ROWB_;
        rowb[nt][2] = (unsigned int)(rU - h0 + 3) * ROWB_;
        const int cs[3] = {cL, pw, cR};
#pragma unroll
        for (int j = 0; j < 3; ++j)
            colb[nt][j] = (unsigned int)(cs[j] - (w0 - 3)) * 128u
                        + (unsigned int)(((cs[j] + kq) & 7) * 16);
    }

    const char* wfb = (const char*)wfrag;
    const unsigned int aoff = (unsigned int)lane * 16u;

    // acc init = bias
    f32x4 acc[2][2];
#pragma unroll
    for (int mtl = 0; mtl < 2; ++mtl) {
        const f32x4 bv = *(const f32x4*)(bias + (mtb + mtl) * 16 + kq * 4);
#pragma unroll
        for (int nt = 0; nt < 2; ++nt)
#pragma unroll
            for (int r = 0; r < 4; ++r) acc[mtl][nt][r] = bv[r];
    }

    __syncthreads();   // staging complete

    // ---- K loop: 18 steps; B dist-1 (LDS), A dist-2 (global) prefetch ----
    bf16x8 bcur[2], bnxt[2], a0[2], a1[2], a2[2];
#pragma unroll
    for (int nt = 0; nt < 2; ++nt)
        bcur[nt] = *(const bf16x8*)(lx + rowb[nt][0] + colb[nt][0]);
#pragma unroll
    for (int mtl = 0; mtl < 2; ++mtl) {
        a0[mtl] = *(const bf16x8*)(wfb + (unsigned int)((0 * 4 + mtb + mtl) * 1024) + aoff);
        a1[mtl] = *(const bf16x8*)(wfb + (unsigned int)((1 * 4 + mtb + mtl) * 1024) + aoff);
    }

#pragma unroll
    for (int s = 0; s < 18; ++s) {
        if (s < 17) {
            const int sn = s + 1;
            const int tap = sn >> 1, hf = sn & 1;
            const int i = tap / 3, j = tap % 3;
#pragma unroll
            for (int nt = 0; nt < 2; ++nt) {
                unsigned int a = rowb[nt][i] + colb[nt][j];
                if (hf) a ^= 64u;                  // ch-group +4 under swizzle
                bnxt[nt] = *(const bf16x8*)(lx + a);
            }
        }
        if (s < 16) {
#pragma unroll
            for (int mtl = 0; mtl < 2; ++mtl)
                a2[mtl] = *(const bf16x8*)(wfb
                            + (unsigned int)(((s + 2) * 4 + mtb + mtl) * 1024) + aoff);
        }
#pragma unroll
        for (int mtl = 0; mtl < 2; ++mtl)
#pragma unroll
            for (int nt = 0; nt < 2; ++nt)
                acc[mtl][nt] = __builtin_amdgcn_mfma_f32_16x16x32_bf16(
                    a0[mtl], bcur[nt], acc[mtl][nt], 0, 0, 0);
#pragma unroll
        for (int nt = 0; nt < 2; ++nt) bcur[nt] = bnxt[nt];
#pragma unroll
        for (int mtl = 0; mtl < 2; ++mtl) { a0[mtl] = a1[mtl]; a1[mtl] = a2[mtl]; }
    }

    // ---- Epilogue: out[b][o][h][w] (w always < W_: exact chunking) ----
#pragma unroll
    for (int mtl = 0; mtl < 2; ++mtl) {
#pragma unroll
        for (int nt = 0; nt < 2; ++nt) {
            const int w = w0 + nt * 16 + l15;
            const unsigned int ob =
                ((unsigned int)(b * O_ + (mtb + mtl) * 16 + kq * 4) * (unsigned int)H_
                 + (unsigned int)h) * (unsigned int)W_ + (unsigned int)w;
#pragma unroll
            for (int r = 0; r < 4; ++r)
                out[ob + (unsigned int)r * 64000u] = acc[mtl][nt][r];
        }
    }
}

extern "C" void kernel_launch(void* const* d_in, const int* in_sizes, int n_in,
                              void* d_out, int out_size, void* d_ws, size_t ws_size,
                              hipStream_t stream) {
    const float* x      = (const float*)d_in[0];   // (8,64,80,800)
    const float* dh     = (const float*)d_in[1];   // (8,1,800)
    const float* dw     = (const float*)d_in[2];   // (8,1,800)
    const float* weight = (const float*)d_in[3];   // (9,64,64)
    const float* bias   = (const float*)d_in[4];   // (64,)
    float* out = (float*)d_out;

    unsigned short* wfrag = (unsigned short*)d_ws; // 73,728 B only

    k_wfrag<<<dim3(144), 256, 0, stream>>>(weight, wfrag);
    k_main<<<dim3(NCHM * (H_ / 4) * B_), 512, 0, stream>>>(x, wfrag, dh, dw, bias, out);
}

// Round 4
// 292.210 us; speedup vs baseline: 1.0620x; 1.0533x over previous
//
#include <hip/hip_runtime.h>

// Problem constants
#define B_  8
#define C_  64
#define O_  64
#define H_  80
#define W_  800
#define NCHM   25          // main kernel: 800/32 exact 32-px chunks

#define ROWS_  10          // staged halo rows: h0-3 .. h0+6 (4 output rows)
#define ROWPX_ 44          // staged cols w0-4 .. w0+39 (quad-aligned)
#define ROWB_  (ROWPX_ * 128)          // 5632 B per staged row
#define LDSX_BYTES (ROWS_ * ROWB_)     // 56320 B -> 2 blocks/CU @ 512 thr
#define NTASK  3520        // 10 rows * 32 ch-pairs * 11 px-quads

typedef short bf16x8 __attribute__((ext_vector_type(8)));
typedef float f32x4  __attribute__((ext_vector_type(4)));

__device__ __forceinline__ unsigned short f2bf(float f) {
    unsigned int u = __float_as_uint(f);
    unsigned int r = u + 0x7FFFu + ((u >> 16) & 1u);   // RNE
    return (unsigned short)(r >> 16);
}

// ---------------------------------------------------------------------------
// Kernel 1: pre-swizzle weight (9,O,C) fp32 into exact A-fragment order, bf16.
// ---------------------------------------------------------------------------
__global__ void k_wfrag(const float* __restrict__ wt, unsigned short* __restrict__ wf) {
    const int t = blockIdx.x * 256 + threadIdx.x;   // < 36864
    const int j    = t & 7;
    const int lane = (t >> 3) & 63;
    const int mt   = (t >> 9) & 3;
    const int ks   = t >> 11;                       // 0..17
    const int tap  = ks >> 1, hf = ks & 1;
    const int o = mt * 16 + (lane & 15);
    const int c = hf * 32 + (lane >> 4) * 8 + j;
    wf[t] = f2bf(wt[(tap * 64 + o) * 64 + c]);
}

// ---------------------------------------------------------------------------
// Kernel 2: FUSED transpose + gather-GEMM, single pass over x.
// Block = 512 thr = 8 waves over (4 h rows) x (2 o-halves); 32-px chunk.
//
// Stage v2 (fixes round-3's latency-bound stage): 3520 tasks
// (row 0..9, ch-pair 0..31, px-quad 0..10); thread t handles tasks
// t, t+512, ... (7 iterations). Per task: 2 ALIGNED coalesced float4 loads
// (4 px of ch 2cp and 2cp+1; 11-lane runs of 176 contiguous bytes) ->
// 4 RNE packs -> 4 ds_write_b32 into the swizzled px-major bf16 layout:
//   lx[row*5632 + p*128 + ((g + colabs)&7)*16 + (cp&3)*4],  g = cp>>2.
// All 512 threads active (was 40/64 lanes); 14 vector loads/thread (was 80
// scalar) across 7 independent unrolled tasks -> loads pipeline within the
// 128-VGPR budget. Edge quads (colabs<0 or >=W) are skipped; the gather only
// reads staged offsets 1..40 of 0..43, so skipped slots are never read.
//
// Gather/K-loop/epilogue identical to verified versions (ROWB 5632, base w0-4).
// ---------------------------------------------------------------------------
__global__ void __launch_bounds__(512, 4)
k_main(const float* __restrict__ x,
       const unsigned short* __restrict__ wfrag,
       const float* __restrict__ dh, const float* __restrict__ dw,
       const float* __restrict__ bias, float* __restrict__ out) {
    __shared__ char lx[LDSX_BYTES];
    const int tid  = threadIdx.x;
    const int wave = tid >> 6, lane = tid & 63;

    const unsigned int flat = blockIdx.x;           // 0..3999
    const int b = flat & 7;                         // XCD swizzle: batch per XCD
    const unsigned int l = flat >> 3;               // 0..499
    const int chunk = l % NCHM;
    const int hq    = l / NCHM;                     // 0..19
    const int h0 = hq * 4;
    const int w0 = chunk * 32;
    const int h   = h0 + (wave & 3);
    const int mtb = (wave >> 2) * 2;                // o-half: mt in {mtb, mtb+1}
    const int l15 = lane & 15, kq = lane >> 4;

    // ---- Fused stage v2: x fp32 -> lx bf16 (transpose+convert+swizzle) ----
    {
        const int wq0 = w0 - 4;
#pragma unroll
        for (int it = 0; it < 7; ++it) {
            const int T = tid + it * 512;
            if (T < NTASK) {
                const int row = T / 352;            // 0..9
                const int rem = T - row * 352;
                const int cp  = rem / 11;           // ch-pair 0..31
                const int q   = rem - cp * 11;      // px-quad 0..10
                const int p0  = 4 * q;              // px slot base
                const int ca  = wq0 + p0;           // absolute col of quad
                if (ca >= 0 && ca + 3 < W_) {
                    int ar = h0 - 3 + row;
                    ar = ar < 0 ? 0 : (ar > H_ - 1 ? H_ - 1 : ar);
                    const int c0 = 2 * cp;
                    const float* s0 = x + ((size_t)(b * C_ + c0) * H_ + ar) * W_ + ca;
                    const f32x4 v0 = *(const f32x4*)s0;
                    const f32x4 v1 = *(const f32x4*)(s0 + (size_t)(H_ * W_));
                    const int g = cp >> 2, widx = cp & 3;
                    char* rbase = lx + row * ROWB_ + widx * 4;
#pragma unroll
                    for (int i = 0; i < 4; ++i) {
                        const unsigned int u = (unsigned int)f2bf(v0[i])
                                             | ((unsigned int)f2bf(v1[i]) << 16);
                        *(unsigned int*)(rbase + (p0 + i) * 128
                                         + (((g + ca + i) & 7) << 4)) = u;
                    }
                }
            }
        }
    }

    // ---- Per-pixel gather addresses (LDS byte offsets) ----
    // 25*32 == 800 exactly: pw < W_ always, no clamps needed.
    unsigned int rowb[2][3], colb[2][3];
#pragma unroll
    for (int nt = 0; nt < 2; ++nt) {
        const int pw  = w0 + nt * 16 + l15;
        const int dhi = (int)dh[b * W_ + pw];
        const int dwi = (int)dw[b * W_ + pw];
        int rD = h - dhi;   if (rD < 0) rD = -rD;
        const int rU = (h + dhi < H_) ? (h + dhi) : h;
        int cL = pw - dwi;  if (cL < 0) cL = -cL;
        const int cR = (pw + dwi < W_) ? (pw + dwi) : (2 * W_ - 1 - pw - dwi);
        rowb[nt][0] = (unsigned int)(rD - h0 + 3) * ROWB_;
        rowb[nt][1] = (unsigned int)(h  - h0 + 3) * ROWB_;
        rowb[nt][2] = (unsigned int)(rU - h0 + 3) * ROWB_;
        const int cs[3] = {cL, pw, cR};
#pragma unroll
        for (int j = 0; j < 3; ++j)
            colb[nt][j] = (unsigned int)(cs[j] - (w0 - 4)) * 128u
                        + (unsigned int)(((cs[j] + kq) & 7) * 16);
    }

    const char* wfb = (const char*)wfrag;
    const unsigned int aoff = (unsigned int)lane * 16u;

    // acc init = bias
    f32x4 acc[2][2];
#pragma unroll
    for (int mtl = 0; mtl < 2; ++mtl) {
        const f32x4 bv = *(const f32x4*)(bias + (mtb + mtl) * 16 + kq * 4);
#pragma unroll
        for (int nt = 0; nt < 2; ++nt)
#pragma unroll
            for (int r = 0; r < 4; ++r) acc[mtl][nt][r] = bv[r];
    }

    __syncthreads();   // staging complete

    // ---- K loop: 18 steps; B dist-1 (LDS), A dist-2 (global) prefetch ----
    bf16x8 bcur[2], bnxt[2], a0[2], a1[2], a2[2];
#pragma unroll
    for (int nt = 0; nt < 2; ++nt)
        bcur[nt] = *(const bf16x8*)(lx + rowb[nt][0] + colb[nt][0]);
#pragma unroll
    for (int mtl = 0; mtl < 2; ++mtl) {
        a0[mtl] = *(const bf16x8*)(wfb + (unsigned int)((0 * 4 + mtb + mtl) * 1024) + aoff);
        a1[mtl] = *(const bf16x8*)(wfb + (unsigned int)((1 * 4 + mtb + mtl) * 1024) + aoff);
    }

#pragma unroll
    for (int s = 0; s < 18; ++s) {
        if (s < 17) {
            const int sn = s + 1;
            const int tap = sn >> 1, hf = sn & 1;
            const int i = tap / 3, j = tap % 3;
#pragma unroll
            for (int nt = 0; nt < 2; ++nt) {
                unsigned int a = rowb[nt][i] + colb[nt][j];
                if (hf) a ^= 64u;                  // ch-group +4 under swizzle
                bnxt[nt] = *(const bf16x8*)(lx + a);
            }
        }
        if (s < 16) {
#pragma unroll
            for (int mtl = 0; mtl < 2; ++mtl)
                a2[mtl] = *(const bf16x8*)(wfb
                            + (unsigned int)(((s + 2) * 4 + mtb + mtl) * 1024) + aoff);
        }
#pragma unroll
        for (int mtl = 0; mtl < 2; ++mtl)
#pragma unroll
            for (int nt = 0; nt < 2; ++nt)
                acc[mtl][nt] = __builtin_amdgcn_mfma_f32_16x16x32_bf16(
                    a0[mtl], bcur[nt], acc[mtl][nt], 0, 0, 0);
#pragma unroll
        for (int nt = 0; nt < 2; ++nt) bcur[nt] = bnxt[nt];
#pragma unroll
        for (int mtl = 0; mtl < 2; ++mtl) { a0[mtl] = a1[mtl]; a1[mtl] = a2[mtl]; }
    }

    // ---- Epilogue: out[b][o][h][w] (w always < W_: exact chunking) ----
#pragma unroll
    for (int mtl = 0; mtl < 2; ++mtl) {
#pragma unroll
        for (int nt = 0; nt < 2; ++nt) {
            const int w = w0 + nt * 16 + l15;
            const unsigned int ob =
                ((unsigned int)(b * O_ + (mtb + mtl) * 16 + kq * 4) * (unsigned int)H_
                 + (unsigned int)h) * (unsigned int)W_ + (unsigned int)w;
#pragma unroll
            for (int r = 0; r < 4; ++r)
                out[ob + (unsigned int)r * 64000u] = acc[mtl][nt][r];
        }
    }
}

extern "C" void kernel_launch(void* const* d_in, const int* in_sizes, int n_in,
                              void* d_out, int out_size, void* d_ws, size_t ws_size,
                              hipStream_t stream) {
    const float* x      = (const float*)d_in[0];   // (8,64,80,800)
    const float* dh     = (const float*)d_in[1];   // (8,1,800)
    const float* dw     = (const float*)d_in[2];   // (8,1,800)
    const float* weight = (const float*)d_in[3];   // (9,64,64)
    const float* bias   = (const float*)d_in[4];   // (64,)
    float* out = (float*)d_out;

    unsigned short* wfrag = (unsigned short*)d_ws; // 73,728 B only

    k_wfrag<<<dim3(144), 256, 0, stream>>>(weight, wfrag);
    k_main<<<dim3(NCHM * (H_ / 4) * B_), 512, 0, stream>>>(x, wfrag, dh, dw, bias, out);
}